// Round 19
// baseline (165.282 us; speedup 1.0000x reference)
//
#include <hip/hip_runtime.h>
#include <math.h>

#define B_TOT   1024
#define S_DIM   64
#define N_DIM   256
#define UNFOLDS 12
#define EPSF    1e-8f
#define L2E     1.4426950408889634f
#define KMAX    256
#define ECLAMP  1073741824.0f   // 2^30: clamp err <= 2^-30; quad product <= 2^121 (finite)

// Guaranteed-native transcendentals.
#if defined(__has_builtin)
#  if __has_builtin(__builtin_amdgcn_exp2f)
#    define FEXP2(x) __builtin_amdgcn_exp2f(x)
#  endif
#  if __has_builtin(__builtin_amdgcn_rcpf)
#    define FRCP(x) __builtin_amdgcn_rcpf(x)
#  endif
#endif
#ifndef FEXP2
__device__ __forceinline__ float __fexp2_asm(float x){ float r; asm("v_exp_f32 %0, %1" : "=v"(r) : "v"(x)); return r; }
#  define FEXP2(x) __fexp2_asm(x)
#endif
#ifndef FRCP
__device__ __forceinline__ float __frcp_asm(float x){ float r; asm("v_rcp_f32 %0, %1" : "=v"(r) : "v"(x)); return r; }
#  define FRCP(x) __frcp_asm(x)
#endif

__device__ __forceinline__ float softplus_f(float x) {
    return log1pf(expf(x));
}

// Montgomery batch-inversion quad: 4 sigmoids r_i = 1/(1+e_i) share ONE v_rcp.
// One param float4 p (same synapse), 4 v values (4 batches). ~1ulp exact.
// All macro locals underscore-prefixed (R9 lesson: caller-name collision).
#define MQUAD(p, v0, v1, v2, v3, m0, d0, m1, d1, m2, d2, m3, d3)            \
    {                                                                       \
        float _t0 = fmaf(p.x, v0, p.y);                                     \
        float _t1 = fmaf(p.x, v1, p.y);                                     \
        float _t2 = fmaf(p.x, v2, p.y);                                     \
        float _t3 = fmaf(p.x, v3, p.y);                                     \
        float _e0 = fminf(FEXP2(_t0), ECLAMP);                              \
        float _e1 = fminf(FEXP2(_t1), ECLAMP);                              \
        float _e2 = fminf(FEXP2(_t2), ECLAMP);                              \
        float _e3 = fminf(FEXP2(_t3), ECLAMP);                              \
        float _a0 = 1.0f + _e0, _a1 = 1.0f + _e1;                           \
        float _a2 = 1.0f + _e2, _a3 = 1.0f + _e3;                           \
        float _b01 = _a0 * _a1, _b23 = _a2 * _a3;                           \
        float _ip   = FRCP(_b01 * _b23);                                    \
        float _ip01 = _b23 * _ip, _ip23 = _b01 * _ip;                       \
        float _r0 = _a1 * _ip01, _r1 = _a0 * _ip01;                         \
        float _r2 = _a3 * _ip23, _r3 = _a2 * _ip23;                         \
        m0 = fmaf(p.w, _r0, m0); d0 = fmaf(p.z, _r0, d0);                   \
        m1 = fmaf(p.w, _r1, m1); d1 = fmaf(p.z, _r1, d1);                   \
        m2 = fmaf(p.w, _r2, m2); d2 = fmaf(p.z, _r2, d2);                   \
        m3 = fmaf(p.w, _r3, m3); d3 = fmaf(p.z, _r3, d3);                   \
    }

// Sensory params {A,B,WE,WEr} (s-major, j-contiguous), per-j combine constants,
// and wmax reset. sigmoid(sigma*(v-mu)) = 1/(1+exp2(A*v+B)).
__global__ void ltc_precompute_s(const float* __restrict__ gleak, const float* __restrict__ vleak,
                                 const float* __restrict__ cm,
                                 const float* __restrict__ sw,    const float* __restrict__ ssig,
                                 const float* __restrict__ smu,   const float* __restrict__ serev,
                                 const float* __restrict__ smask,
                                 float4* __restrict__ s4, float4* __restrict__ pj,
                                 int* __restrict__ wmax)
{
    const int idx = blockIdx.x * blockDim.x + threadIdx.x;
    if (idx < S_DIM * N_DIM) {
        float we = softplus_f(sw[idx]) * smask[idx];
        float sg = ssig[idx];
        float4 o;
        o.x = -L2E * sg;
        o.y =  L2E * sg * smu[idx];
        o.z =  we;
        o.w =  we * serev[idx];
        s4[idx] = o;
    }
    if (idx < N_DIM) {
        float g = softplus_f(gleak[idx]);
        float4 o;
        o.x = softplus_f(cm[idx]) * (float)UNFOLDS;  // cm_t
        o.y = g;
        o.z = g * vleak[idx];
        o.w = 0.0f;
        pj[idx] = o;
    }
    if (idx < 4) wmax[idx] = 0;
}

// Fused precompute + parallel compaction. One block per column j; ballot
// prefix-scan compacts live rows. pc is k-major [k][j] float4 (coalesced).
// The presynaptic index i rides in the LOW MANTISSA BYTE of p.z (WE):
// perturbs WE by <= 255 ulp (~1.5e-5 rel, vs 1.16e-2 tolerance) and removes
// the separate offset stream entirely (1 fewer VMEM load per quad).
// p.w = p.z_embedded * erev (erev = +-1 -> exact sign copy, num/den consistent).
// Zero-pad rows to KMAX: all-zero param -> index 0, weight 0, contributes 0.
// Per-64-col max live count -> wmax[j>>6].
__global__ __launch_bounds__(256)
void ltc_compact(const float* __restrict__ w,    const float* __restrict__ sigma,
                 const float* __restrict__ mu,   const float* __restrict__ erev,
                 const float* __restrict__ mask,
                 float4* __restrict__ pc, int* __restrict__ wmax)
{
    const int j = blockIdx.x;
    const int i = threadIdx.x;
    const int idx = i * N_DIM + j;

    const float mk = mask[idx];
    const bool live = mk > 0.0f;
    float we = softplus_f(w[idx]) * mk;
    float sg = sigma[idx];

    // embed index: low 8 mantissa bits of WE := i
    unsigned int zb = __float_as_uint(we);
    zb = (zb & 0xFFFFFF00u) | (unsigned int)i;
    const float wez = __uint_as_float(zb);

    float4 o;
    o.x = -L2E * sg;
    o.y =  L2E * sg * mu[idx];
    o.z =  wez;
    o.w =  wez * erev[idx];

    const int lane = i & 63, wv = i >> 6;
    const unsigned long long ball = __ballot(live);
    const int lpre = __popcll(ball & ((1ull << lane) - 1ull));
    __shared__ int wcnt[4];
    if (lane == 0) wcnt[wv] = __popcll(ball);
    __syncthreads();
    int base = 0;
    #pragma unroll
    for (int ww = 0; ww < 4; ++ww) base += (ww < wv) ? wcnt[ww] : 0;
    const int total = wcnt[0] + wcnt[1] + wcnt[2] + wcnt[3];

    if (live) {
        pc[(base + lpre) * N_DIM + j] = o;
    }
    for (int k = total + i; k < KMAX; k += 256) {   // zero-pad (exact zeros)
        pc[k * N_DIM + j] = make_float4(0.f, 0.f, 0.f, 0.f);
    }
    if (i == 0) atomicMax(&wmax[j >> 6], total);
}

// 1024 threads/block, 256 blocks, 4 batches each. j = tid&255, q = tid>>8
// (0..3); q covers a contiguous quarter of the compacted k-range, bounded by
// the per-64-col-group max padded to a multiple of 32 (clean unroll-8 —
// R18 showed exact-ceil's remainder loop costs more than the 7% padding).
// Per quad: ONE coalesced float4 load (param + embedded index) + 1 b128 LDS
// gather + scalar Montgomery quad (1 rcp / 4 sigmoids).
__global__ __launch_bounds__(1024, 2)
void ltc_main(const float* __restrict__ inputs, const float* __restrict__ state,
              const float4* __restrict__ pc, const int* __restrict__ wmax,
              const float4* __restrict__ s4, const float4* __restrict__ pj,
              float* __restrict__ out)
{
    __shared__ float4 v4[N_DIM];        // v[i], component = batch
    __shared__ float4 pnum[4][N_DIM];   // partials [q][j]
    __shared__ float4 pden[4][N_DIM];
    __shared__ float  in_lds[4][S_DIM];

    const int tid = threadIdx.x;
    const int j   = tid & (N_DIM - 1);
    const int q   = tid >> 8;
    const int b0  = blockIdx.x << 2;

    ((float*)v4)[(j << 2) + q] = state[(b0 + q) * N_DIM + j];
    if (tid < 4 * S_DIM) in_lds[tid >> 6][tid & 63] = inputs[b0 * S_DIM + tid];

    const float4 c = pj[j];
    const float cmt = c.x, gl = c.y, glv = c.z;
    const float cg  = cmt + gl + EPSF;

    // per-wave-group uniform quad count: pad group max to multiple of 32,
    // quarter it (multiple of 8 -> clean unroll-8, no remainder loop)
    const int wl  = wmax[j >> 6];
    const int U4w = ((wl + 31) & ~31) >> 2;
    __syncthreads();

    // ---- sensory pass: q covers s in [16q, 16q+16), Montgomery quads ----
    float n0 = 0.f, n1 = 0.f, n2 = 0.f, n3 = 0.f;
    float d0 = 0.f, d1 = 0.f, d2 = 0.f, d3 = 0.f;
    {
        const float4* __restrict__ sr = s4 + (q << 4) * N_DIM + j;
        const int sb = q << 4;
        #pragma unroll 4
        for (int s = 0; s < 16; ++s) {
            const float4 p = sr[s * N_DIM];
            const float i0 = in_lds[0][sb + s];
            const float i1 = in_lds[1][sb + s];
            const float i2 = in_lds[2][sb + s];
            const float i3 = in_lds[3][sb + s];
            MQUAD(p, i0, i1, i2, i3, n0, d0, n1, d1, n2, d2, n3, d3)
        }
    }
    pnum[q][j] = make_float4(n0, n1, n2, n3);
    pden[q][j] = make_float4(d0, d1, d2, d3);
    __syncthreads();

    // redundant sensory reduce into registers (all q identical)
    float4 sn = make_float4(0.f, 0.f, 0.f, 0.f);
    float4 sd = make_float4(0.f, 0.f, 0.f, 0.f);
    #pragma unroll
    for (int qq = 0; qq < 4; ++qq) {
        const float4 a = pnum[qq][j], b = pden[qq][j];
        sn.x += a.x; sn.y += a.y; sn.z += a.z; sn.w += a.w;
        sd.x += b.x; sd.y += b.y; sd.z += b.z; sd.w += b.w;
    }
    __syncthreads();   // pnum/pden reused below

    // ---- 12 ODE unfolds over the compacted list ----
    const float4* __restrict__ pr = pc + (q * U4w) * N_DIM + j;

    #pragma unroll 1
    for (int step = 0; step < UNFOLDS; ++step) {
        float m0 = 0.f, m1 = 0.f, m2 = 0.f, m3 = 0.f;
        float h0 = 0.f, h1 = 0.f, h2 = 0.f, h3 = 0.f;

        #pragma unroll 8
        for (int t = 0; t < U4w; ++t) {
            const float4 p   = pr[t * N_DIM];   // coalesced dwordx4 (param+index)
            const int    off = (int)((__float_as_uint(p.z) & 0xFFu) << 4);
            const float4 vv  = *(const float4*)((const char*)v4 + off);  // b128 gather
            MQUAD(p, vv.x, vv.y, vv.z, vv.w, m0, h0, m1, h1, m2, h2, m3, h3)
        }

        const float4 vo = v4[j];   // read old v BEFORE the barrier
        pnum[q][j] = make_float4(m0, m1, m2, m3);
        pden[q][j] = make_float4(h0, h1, h2, h3);
        __syncthreads();

        // redundant combine in all q-groups (bitwise-identical results);
        // Montgomery for the 4 division denominators (all > cg > 0).
        float4 tn = sn, td = sd;
        #pragma unroll
        for (int qq = 0; qq < 4; ++qq) {
            const float4 a = pnum[qq][j], b = pden[qq][j];
            tn.x += a.x; tn.y += a.y; tn.z += a.z; tn.w += a.w;
            td.x += b.x; td.y += b.y; td.z += b.z; td.w += b.w;
        }
        const float g0 = cg + td.x, g1 = cg + td.y;
        const float g2 = cg + td.z, g3 = cg + td.w;
        const float b01 = g0 * g1, b23 = g2 * g3;
        const float ip   = FRCP(b01 * b23);
        const float ip01 = b23 * ip, ip23 = b01 * ip;
        float4 vn;
        vn.x = (fmaf(cmt, vo.x, glv) + tn.x) * (g1 * ip01);
        vn.y = (fmaf(cmt, vo.y, glv) + tn.y) * (g0 * ip01);
        vn.z = (fmaf(cmt, vo.z, glv) + tn.z) * (g3 * ip23);
        vn.w = (fmaf(cmt, vo.w, glv) + tn.w) * (g2 * ip23);
        v4[j] = vn;                // 4 writers, identical bits — benign
        __syncthreads();
    }

    out[(b0 + q) * N_DIM + j] = ((const float*)v4)[(j << 2) + q];
}

extern "C" void kernel_launch(void* const* d_in, const int* in_sizes, int n_in,
                              void* d_out, int out_size, void* d_ws, size_t ws_size,
                              hipStream_t stream)
{
    const float* inputs = (const float*)d_in[0];
    const float* state  = (const float*)d_in[1];
    const float* gleak  = (const float*)d_in[2];
    const float* vleak  = (const float*)d_in[3];
    const float* cm     = (const float*)d_in[4];
    const float* w      = (const float*)d_in[5];
    const float* sigma  = (const float*)d_in[6];
    const float* mu     = (const float*)d_in[7];
    const float* erev   = (const float*)d_in[8];
    const float* sw     = (const float*)d_in[9];
    const float* ssig   = (const float*)d_in[10];
    const float* smu    = (const float*)d_in[11];
    const float* serev  = (const float*)d_in[12];
    const float* mask   = (const float*)d_in[13];
    const float* smask  = (const float*)d_in[14];

    float4* s4 = (float4*)d_ws;                        // [S*N]    = 256 KiB
    float4* pj = s4 + S_DIM * N_DIM;                   // [N]      = 4 KiB
    float4* pc = pj + N_DIM;                           // [KMAX*N] = 1 MiB
    int* wmax = (int*)(pc + KMAX * N_DIM);             // [4]

    ltc_precompute_s<<<(S_DIM * N_DIM + 255) / 256, 256, 0, stream>>>(
        gleak, vleak, cm, sw, ssig, smu, serev, smask, s4, pj, wmax);

    ltc_compact<<<N_DIM, 256, 0, stream>>>(w, sigma, mu, erev, mask, pc, wmax);

    ltc_main<<<B_TOT / 4, 1024, 0, stream>>>(inputs, state, pc, wmax,
                                             s4, pj, (float*)d_out);
}

// Round 20
// 151.504 us; speedup vs baseline: 1.0909x; 1.0909x over previous
//
#include <hip/hip_runtime.h>
#include <math.h>

#define B_TOT   1024
#define S_DIM   64
#define N_DIM   256
#define UNFOLDS 12
#define EPSF    1e-8f
#define L2E     1.4426950408889634f
#define KMAX    256

// Guaranteed-native transcendentals.
#if defined(__has_builtin)
#  if __has_builtin(__builtin_amdgcn_exp2f)
#    define FEXP2(x) __builtin_amdgcn_exp2f(x)
#  endif
#  if __has_builtin(__builtin_amdgcn_rcpf)
#    define FRCP(x) __builtin_amdgcn_rcpf(x)
#  endif
#endif
#ifndef FEXP2
__device__ __forceinline__ float __fexp2_asm(float x){ float r; asm("v_exp_f32 %0, %1" : "=v"(r) : "v"(x)); return r; }
#  define FEXP2(x) __fexp2_asm(x)
#endif
#ifndef FRCP
__device__ __forceinline__ float __frcp_asm(float x){ float r; asm("v_rcp_f32 %0, %1" : "=v"(r) : "v"(x)); return r; }
#  define FRCP(x) __frcp_asm(x)
#endif

__device__ __forceinline__ float softplus_f(float x) {
    return log1pf(expf(x));
}

// Sensory params {A,B,WE,WEr} (s-major, j-contiguous) and per-j combine
// constants. sigmoid(sigma*(v-mu)) = 1/(1+exp2(A*v+B)).
__global__ void ltc_precompute_s(const float* __restrict__ gleak, const float* __restrict__ vleak,
                                 const float* __restrict__ cm,
                                 const float* __restrict__ sw,    const float* __restrict__ ssig,
                                 const float* __restrict__ smu,   const float* __restrict__ serev,
                                 const float* __restrict__ smask,
                                 float4* __restrict__ s4, float4* __restrict__ pj)
{
    const int idx = blockIdx.x * blockDim.x + threadIdx.x;
    if (idx < S_DIM * N_DIM) {
        float we = softplus_f(sw[idx]) * smask[idx];
        float sg = ssig[idx];
        float4 o;
        o.x = -L2E * sg;
        o.y =  L2E * sg * smu[idx];
        o.z =  we;
        o.w =  we * serev[idx];
        s4[idx] = o;
    }
    if (idx < N_DIM) {
        float g = softplus_f(gleak[idx]);
        float4 o;
        o.x = softplus_f(cm[idx]) * (float)UNFOLDS;  // cm_t
        o.y = g;
        o.z = g * vleak[idx];
        o.w = 0.0f;
        pj[idx] = o;
    }
}

// Parallel fused precompute + compaction (R7 mechanism, R6 layouts).
// One block per column j; ballot prefix-scan packs live rows. pc is k-major
// [k][j] float4 (coalesced); pidx is k-major [k][j] u16 RAW row index.
// Pad to a multiple of 4 with zero-weight entries (contribute exactly 0).
// cnt4[j] = padded_count/4 = per-lane quad count (uniform across q since
// lane q takes k = 4t+q).
__global__ __launch_bounds__(256)
void ltc_compact(const float* __restrict__ w,    const float* __restrict__ sigma,
                 const float* __restrict__ mu,   const float* __restrict__ erev,
                 const float* __restrict__ mask,
                 float4* __restrict__ pc, unsigned short* __restrict__ pidx,
                 int* __restrict__ cnt4)
{
    const int j = blockIdx.x;
    const int i = threadIdx.x;
    const int idx = i * N_DIM + j;

    const float mk = mask[idx];
    const bool live = mk > 0.0f;
    float we = softplus_f(w[idx]) * mk;
    float sg = sigma[idx];
    float4 o;
    o.x = -L2E * sg;
    o.y =  L2E * sg * mu[idx];
    o.z =  we;
    o.w =  we * erev[idx];

    const int lane = i & 63, wv = i >> 6;
    const unsigned long long ball = __ballot(live);
    const int lpre = __popcll(ball & ((1ull << lane) - 1ull));
    __shared__ int wcnt[4];
    if (lane == 0) wcnt[wv] = __popcll(ball);
    __syncthreads();
    int base = 0;
    #pragma unroll
    for (int ww = 0; ww < 4; ++ww) base += (ww < wv) ? wcnt[ww] : 0;
    const int total = wcnt[0] + wcnt[1] + wcnt[2] + wcnt[3];

    if (live) {
        const int pos = base + lpre;
        pc[pos * N_DIM + j] = o;
        pidx[pos * N_DIM + j] = (unsigned short)i;
    }
    const int K4 = (total + 3) & ~3;
    for (int k = total + i; k < K4; k += 256) {   // zero-pad (exact zeros)
        pc[k * N_DIM + j] = make_float4(0.f, 0.f, 0.f, 0.f);
        pidx[k * N_DIM + j] = 0;
    }
    if (i == 0) cnt4[j] = K4 >> 2;
}

// ---- main: byte-for-byte R6 structure (best measured: 159.5 µs profiled).
// 1024 threads/block, 256 blocks, 4 batches each. j = tid&255, q = tid>>8
// (0..3); q-group strides the compacted list k = 4t+q, t < cnt4[j] (per-lane
// bound; effective trip = wave max ~= 38 < R10's padded 40). Native exp2+rcp
// (R6 mix measured faster than Montgomery), no clamp, unroll 2.
__global__ __launch_bounds__(1024, 2)
void ltc_main(const float* __restrict__ inputs, const float* __restrict__ state,
              const float4* __restrict__ pc, const unsigned short* __restrict__ pidx,
              const int* __restrict__ cnt4,
              const float4* __restrict__ s4, const float4* __restrict__ pj,
              float* __restrict__ out)
{
    __shared__ float4 v4[N_DIM];        // v[i], component = batch
    __shared__ float4 pnum[4][N_DIM];   // partials [q][j]
    __shared__ float4 pden[4][N_DIM];
    __shared__ float  in_lds[4][S_DIM];

    const int tid = threadIdx.x;
    const int j   = tid & (N_DIM - 1);
    const int q   = tid >> 8;
    const int b0  = blockIdx.x << 2;

    ((float*)v4)[(j << 2) + q] = state[(b0 + q) * N_DIM + j];
    if (tid < 4 * S_DIM) in_lds[tid >> 6][tid & 63] = inputs[b0 * S_DIM + tid];

    const float4 c = pj[j];
    const float cmt = c.x, gl = c.y, glv = c.z;
    const float cg  = cmt + gl + EPSF;
    const int   myc = cnt4[j];
    __syncthreads();

    // ---- sensory pass: q covers s in [16q, 16q+16) ----
    float n0 = 0.f, n1 = 0.f, n2 = 0.f, n3 = 0.f;
    float d0 = 0.f, d1 = 0.f, d2 = 0.f, d3 = 0.f;
    {
        const float4* __restrict__ sr = s4 + (q << 4) * N_DIM + j;
        const int sbase = q << 4;
        #pragma unroll 4
        for (int s = 0; s < 16; ++s) {
            const float4 p = sr[s * N_DIM];
            float e0 = FEXP2(fmaf(p.x, in_lds[0][sbase + s], p.y));
            float e1 = FEXP2(fmaf(p.x, in_lds[1][sbase + s], p.y));
            float e2 = FEXP2(fmaf(p.x, in_lds[2][sbase + s], p.y));
            float e3 = FEXP2(fmaf(p.x, in_lds[3][sbase + s], p.y));
            float r0 = FRCP(1.0f + e0);
            float r1 = FRCP(1.0f + e1);
            float r2 = FRCP(1.0f + e2);
            float r3 = FRCP(1.0f + e3);
            n0 = fmaf(p.w, r0, n0); d0 = fmaf(p.z, r0, d0);
            n1 = fmaf(p.w, r1, n1); d1 = fmaf(p.z, r1, d1);
            n2 = fmaf(p.w, r2, n2); d2 = fmaf(p.z, r2, d2);
            n3 = fmaf(p.w, r3, n3); d3 = fmaf(p.z, r3, d3);
        }
    }
    pnum[q][j] = make_float4(n0, n1, n2, n3);
    pden[q][j] = make_float4(d0, d1, d2, d3);
    __syncthreads();

    // all threads redundantly reduce sensory partials into registers
    float4 sn = make_float4(0.f, 0.f, 0.f, 0.f);
    float4 sd = make_float4(0.f, 0.f, 0.f, 0.f);
    #pragma unroll
    for (int qq = 0; qq < 4; ++qq) {
        const float4 a = pnum[qq][j], b = pden[qq][j];
        sn.x += a.x; sn.y += a.y; sn.z += a.z; sn.w += a.w;
        sd.x += b.x; sd.y += b.y; sd.z += b.z; sd.w += b.w;
    }
    __syncthreads();   // pnum/pden reused below

    // ---- 12 ODE unfolds over the compacted list ----
    const float4*         __restrict__ pr0 = pc   + q * N_DIM + j;
    const unsigned short* __restrict__ ir0 = pidx + q * N_DIM + j;

    #pragma unroll 1
    for (int step = 0; step < UNFOLDS; ++step) {
        float m0 = 0.f, m1 = 0.f, m2 = 0.f, m3 = 0.f;
        float e0_ = 0.f, e1_ = 0.f, e2_ = 0.f, e3_ = 0.f;   // den accumulators

        const float4*         __restrict__ pp = pr0;
        const unsigned short* __restrict__ pi = ir0;
        #pragma unroll 2
        for (int t = 0; t < myc; ++t) {
            const float4 p  = *pp;
            const int    ii = *pi;
            pp += 4 * N_DIM;  pi += 4 * N_DIM;
            const float4 vv = v4[ii];          // LDS gather (sorted idx)
            float e0 = FEXP2(fmaf(p.x, vv.x, p.y));
            float e1 = FEXP2(fmaf(p.x, vv.y, p.y));
            float e2 = FEXP2(fmaf(p.x, vv.z, p.y));
            float e3 = FEXP2(fmaf(p.x, vv.w, p.y));
            float r0 = FRCP(1.0f + e0);
            float r1 = FRCP(1.0f + e1);
            float r2 = FRCP(1.0f + e2);
            float r3 = FRCP(1.0f + e3);
            m0 = fmaf(p.w, r0, m0); e0_ = fmaf(p.z, r0, e0_);
            m1 = fmaf(p.w, r1, m1); e1_ = fmaf(p.z, r1, e1_);
            m2 = fmaf(p.w, r2, m2); e2_ = fmaf(p.z, r2, e2_);
            m3 = fmaf(p.w, r3, m3); e3_ = fmaf(p.z, r3, e3_);
        }

        const float4 vo = v4[j];   // read old v BEFORE the barrier
        pnum[q][j] = make_float4(m0, m1, m2, m3);
        pden[q][j] = make_float4(e0_, e1_, e2_, e3_);
        __syncthreads();

        // redundant combine in all q-groups (bitwise-identical results)
        float4 tn = sn, td = sd;
        #pragma unroll
        for (int qq = 0; qq < 4; ++qq) {
            const float4 a = pnum[qq][j], b = pden[qq][j];
            tn.x += a.x; tn.y += a.y; tn.z += a.z; tn.w += a.w;
            td.x += b.x; td.y += b.y; td.z += b.z; td.w += b.w;
        }
        float4 vn;
        vn.x = (fmaf(cmt, vo.x, glv) + tn.x) * FRCP(cg + td.x);
        vn.y = (fmaf(cmt, vo.y, glv) + tn.y) * FRCP(cg + td.y);
        vn.z = (fmaf(cmt, vo.z, glv) + tn.z) * FRCP(cg + td.z);
        vn.w = (fmaf(cmt, vo.w, glv) + tn.w) * FRCP(cg + td.w);
        v4[j] = vn;                // 4 writers, identical bits — benign
        __syncthreads();
    }

    out[(b0 + q) * N_DIM + j] = ((const float*)v4)[(j << 2) + q];
}

extern "C" void kernel_launch(void* const* d_in, const int* in_sizes, int n_in,
                              void* d_out, int out_size, void* d_ws, size_t ws_size,
                              hipStream_t stream)
{
    const float* inputs = (const float*)d_in[0];
    const float* state  = (const float*)d_in[1];
    const float* gleak  = (const float*)d_in[2];
    const float* vleak  = (const float*)d_in[3];
    const float* cm     = (const float*)d_in[4];
    const float* w      = (const float*)d_in[5];
    const float* sigma  = (const float*)d_in[6];
    const float* mu     = (const float*)d_in[7];
    const float* erev   = (const float*)d_in[8];
    const float* sw     = (const float*)d_in[9];
    const float* ssig   = (const float*)d_in[10];
    const float* smu    = (const float*)d_in[11];
    const float* serev  = (const float*)d_in[12];
    const float* mask   = (const float*)d_in[13];
    const float* smask  = (const float*)d_in[14];

    float4* s4 = (float4*)d_ws;                        // [S*N]    = 256 KiB
    float4* pj = s4 + S_DIM * N_DIM;                   // [N]      = 4 KiB
    float4* pc = pj + N_DIM;                           // [KMAX*N] = 1 MiB
    unsigned short* pidx = (unsigned short*)(pc + KMAX * N_DIM);  // [KMAX][N] = 128 KiB
    int* cnt4 = (int*)(pidx + KMAX * N_DIM);           // [N]

    ltc_precompute_s<<<(S_DIM * N_DIM + 255) / 256, 256, 0, stream>>>(
        gleak, vleak, cm, sw, ssig, smu, serev, smask, s4, pj);

    ltc_compact<<<N_DIM, 256, 0, stream>>>(w, sigma, mu, erev, mask, pc, pidx, cnt4);

    ltc_main<<<B_TOT / 4, 1024, 0, stream>>>(inputs, state, pc, pidx, cnt4,
                                             s4, pj, (float*)d_out);
}